// Round 1
// baseline (395.261 us; speedup 1.0000x reference)
//
#include <hip/hip_runtime.h>
#include <cstdint>

#define N_NODES 100000
#define N_EDGES 1600000
#define N_BATCH 1000
#define LEAK 0.01f

__device__ __forceinline__ float lrelu(float x){ return x > 0.f ? x : LEAK * x; }

// ---------------- graph preprocessing ----------------

__global__ void k_mark_ego(const int* __restrict__ ego, int* __restrict__ egoflag, int* __restrict__ Sflag){
  int i = blockIdx.x * blockDim.x + threadIdx.x;
  if (i < N_BATCH){ int n = ego[i]; egoflag[n] = 1; Sflag[n] = 1; }
}

__global__ void k_node_lin1(const float* __restrict__ feat,
                            const float* __restrict__ Wni1, const float* __restrict__ Wnj1,
                            float* __restrict__ fni1, float* __restrict__ fnj1){
  int n = blockIdx.x * blockDim.x + threadIdx.x;
  if (n >= N_NODES) return;
  float f[16];
  #pragma unroll
  for (int c = 0; c < 16; c++) f[c] = feat[n * 16 + c];
  #pragma unroll
  for (int h = 0; h < 3; h++){
    float a = 0.f, b = 0.f;
    #pragma unroll
    for (int c = 0; c < 16; c++){ a += f[c] * Wni1[h * 16 + c]; b += f[c] * Wnj1[h * 16 + c]; }
    fni1[n * 3 + h] = a; fnj1[n * 3 + h] = b;
  }
}

__global__ void k_mark_S(const int* __restrict__ src, const int* __restrict__ dst,
                         const int* __restrict__ egoflag, int* __restrict__ Sflag){
  int e = blockIdx.x * blockDim.x + threadIdx.x;
  if (e < N_EDGES && egoflag[dst[e]]) Sflag[src[e]] = 1;   // benign race, all write 1
}

__global__ void k_compact(const int* __restrict__ Sflag, int* __restrict__ nodeslot,
                          int* __restrict__ S_ids, int* __restrict__ meta){
  int n = blockIdx.x * blockDim.x + threadIdx.x;
  if (n < N_NODES && Sflag[n]){
    int s = atomicAdd(&meta[0], 1);
    S_ids[s] = n; nodeslot[n] = s;
  }
}

__global__ void k_count(const int* __restrict__ src, const int* __restrict__ dst,
                        const int* __restrict__ Sflag, const int* __restrict__ nodeslot,
                        int* __restrict__ cnt){
  int e = blockIdx.x * blockDim.x + threadIdx.x;
  if (e < N_EDGES && Sflag[dst[e]]) atomicAdd(&cnt[nodeslot[dst[e]]], 1);
}

__global__ void k_scan(const int* __restrict__ cnt, int* __restrict__ rowptr, const int* __restrict__ meta){
  const int S = meta[0];
  __shared__ int buf[1024];
  __shared__ int carryS;
  int t = threadIdx.x;
  if (t == 0) carryS = 0;
  __syncthreads();
  for (int base = 0; base < S; base += 1024){
    int i = base + t;
    int v = (i < S) ? cnt[i] : 0;
    buf[t] = v; __syncthreads();
    for (int off = 1; off < 1024; off <<= 1){
      int add = (t >= off) ? buf[t - off] : 0;
      __syncthreads();
      buf[t] += add;
      __syncthreads();
    }
    int c0 = carryS;
    if (i < S) rowptr[i] = c0 + buf[t] - v;   // exclusive
    __syncthreads();
    if (t == 0) carryS = c0 + buf[1023];
    __syncthreads();
  }
  if (t == 0) rowptr[S] = carryS;
}

__global__ void k_fill(const int* __restrict__ src, const int* __restrict__ dst,
                       const float* __restrict__ enorm,
                       const int* __restrict__ Sflag, const int* __restrict__ nodeslot,
                       const int* __restrict__ rowptr, int* __restrict__ cursor,
                       int* __restrict__ src_csr, float* __restrict__ enorm_csr){
  int e = blockIdx.x * blockDim.x + threadIdx.x;
  if (e < N_EDGES && Sflag[dst[e]]){
    int s = nodeslot[dst[e]];
    int p = rowptr[s] + atomicAdd(&cursor[s], 1);
    src_csr[p] = src[e];
    enorm_csr[p] = enorm[e];
  }
}

// ---------------- layer 1: fused logits + segment softmax + aggregate + Wnode1 ----------------

__global__ __launch_bounds__(256) void k6_layer1(
    const float* __restrict__ feat, const float* __restrict__ fni1, const float* __restrict__ fnj1,
    const int* __restrict__ S_ids, const int* __restrict__ rowptr,
    const int* __restrict__ src_csr, const float* __restrict__ enorm_csr,
    const float* __restrict__ Wnode1, const float* __restrict__ Wfij1,
    const float* __restrict__ attn1, const float* __restrict__ bias1,
    const int* __restrict__ meta, float* __restrict__ hG_S)
{
  __shared__ float Wn1[192 * 17];             // +1 pad per 16-row: bank-conflict free
  for (int i = threadIdx.x; i < 3072; i += 256) Wn1[(i >> 4) * 17 + (i & 15)] = Wnode1[i];
  __syncthreads();
  const int S = meta[0];
  int lane = threadIdx.x & 63;
  int wid = blockIdx.x * (blockDim.x >> 6) + (threadIdx.x >> 6);
  int nw = gridDim.x * (blockDim.x >> 6);
  float wf0 = Wfij1[0], wf1 = Wfij1[1], wf2 = Wfij1[2];
  float at0 = attn1[0], at1 = attn1[1], at2 = attn1[2];
  float b0 = bias1[0], b1 = bias1[1], b2 = bias1[2];
  int hsel = lane >> 4, csel = lane & 15;

  for (int s = wid; s < S; s += nw){
    int n = S_ids[s];
    int j0 = rowptr[s], j1 = rowptr[s + 1];
    float fj0 = fnj1[n * 3 + 0], fj1 = fnj1[n * 3 + 1], fj2 = fnj1[n * 3 + 2];
    // pass A: per-head max of attention logits
    float m0 = -1e30f, m1 = -1e30f, m2 = -1e30f;
    for (int j = j0 + lane; j < j1; j += 64){
      int sn = src_csr[j]; float en = enorm_csr[j];
      float l0 = lrelu(fni1[sn * 3 + 0] + fj0 + en * wf0 + b0);
      float l1 = lrelu(fni1[sn * 3 + 1] + fj1 + en * wf1 + b1);
      float l2 = lrelu(fni1[sn * 3 + 2] + fj2 + en * wf2 + b2);
      m0 = fmaxf(m0, l0 * at0); m1 = fmaxf(m1, l1 * at1); m2 = fmaxf(m2, l2 * at2);
    }
    #pragma unroll
    for (int off = 32; off > 0; off >>= 1){
      m0 = fmaxf(m0, __shfl_xor(m0, off));
      m1 = fmaxf(m1, __shfl_xor(m1, off));
      m2 = fmaxf(m2, __shfl_xor(m2, off));
    }
    // pass B: exp-sum and weighted feat aggregation (lane<48: h=lane/16, c=lane%16)
    float s0 = 0.f, s1 = 0.f, s2 = 0.f, wsum = 0.f;
    for (int base = j0; base < j1; base += 64){
      int j = base + lane;
      float w0 = 0.f, w1 = 0.f, w2 = 0.f; int sn = 0;
      if (j < j1){
        sn = src_csr[j]; float en = enorm_csr[j];
        float l0 = lrelu(fni1[sn * 3 + 0] + fj0 + en * wf0 + b0);
        float l1 = lrelu(fni1[sn * 3 + 1] + fj1 + en * wf1 + b1);
        float l2 = lrelu(fni1[sn * 3 + 2] + fj2 + en * wf2 + b2);
        w0 = __expf(l0 * at0 - m0); w1 = __expf(l1 * at1 - m1); w2 = __expf(l2 * at2 - m2);
      }
      int cnt2 = min(64, j1 - base);
      for (int i = 0; i < cnt2; i++){
        float ww0 = __shfl(w0, i), ww1 = __shfl(w1, i), ww2 = __shfl(w2, i);
        int ssn = __shfl(sn, i);
        s0 += ww0; s1 += ww1; s2 += ww2;
        if (lane < 48){
          float f = feat[ssn * 16 + csel];
          float wh = hsel == 0 ? ww0 : (hsel == 1 ? ww1 : ww2);
          wsum += wh * f;
        }
      }
    }
    float aval = 0.f;
    if (lane < 48 && j1 > j0){
      float sh = hsel == 0 ? s0 : (hsel == 1 ? s1 : s2);
      aval = wsum / sh;
    }
    // epilogue: hG[n, h*64+o] = relu( a[h,:] . Wnode1[h*64+o,:] )
    #pragma unroll
    for (int r = 0; r < 3; r++){
      float acc = 0.f;
      #pragma unroll
      for (int c = 0; c < 16; c++)
        acc += __shfl(aval, r * 16 + c) * Wn1[(r * 64 + lane) * 17 + c];
      hG_S[(long long)s * 192 + r * 64 + lane] = fmaxf(acc, 0.f);
    }
  }
}

// ---------------- ft3 = hG_S @ Wnode3^T (+ f_ni3, f_nj3) ----------------

__global__ __launch_bounds__(256) void k6b_ft3(
    const float* __restrict__ hG_S, const float* __restrict__ Wnode3,
    const float* __restrict__ Wni3, const float* __restrict__ Wnj3,
    const int* __restrict__ meta, float* __restrict__ ft3_S,
    float* __restrict__ fni3_S, float* __restrict__ fnj3_S)
{
  const int S = meta[0];
  int lane = threadIdx.x & 63;
  int wid = blockIdx.x * (blockDim.x >> 6) + (threadIdx.x >> 6);
  int nw = gridDim.x * (blockDim.x >> 6);
  int groups = (S + 7) >> 3;
  const float* w0p = Wnode3 + lane * 192;
  const float* w1p = Wnode3 + (lane + 64) * 192;
  const float* wNp = (lane == 0) ? Wni3 : Wnj3;
  for (int g = wid; g < groups; g += nw){
    float hreg[8][3];
    #pragma unroll
    for (int r = 0; r < 8; r++){
      int slot = g * 8 + r;
      if (slot < S){
        #pragma unroll
        for (int k = 0; k < 3; k++) hreg[r][k] = hG_S[(long long)slot * 192 + lane * 3 + k];
      } else {
        hreg[r][0] = hreg[r][1] = hreg[r][2] = 0.f;
      }
    }
    float acc0[8] = {0,0,0,0,0,0,0,0};
    float acc1[8] = {0,0,0,0,0,0,0,0};
    float accN[8] = {0,0,0,0,0,0,0,0};
    for (int cg = 0; cg < 64; ++cg){
      #pragma unroll
      for (int k = 0; k < 3; k++){
        int c = cg * 3 + k;
        float a0 = w0p[c], a1 = w1p[c], aN = wNp[c];
        #pragma unroll
        for (int r = 0; r < 8; r++){
          float hb = __shfl(hreg[r][k], cg);
          acc0[r] += hb * a0; acc1[r] += hb * a1; accN[r] += hb * aN;
        }
      }
    }
    #pragma unroll
    for (int r = 0; r < 8; r++){
      int slot = g * 8 + r;
      if (slot < S){
        ft3_S[(long long)slot * 128 + lane] = acc0[r];
        ft3_S[(long long)slot * 128 + 64 + lane] = acc1[r];
        if (lane == 0) fni3_S[slot] = accN[r];
        if (lane == 1) fnj3_S[slot] = accN[r];
      }
    }
  }
}

// ---------------- layer 2 (ego nodes only) ----------------

__global__ __launch_bounds__(256) void k8_layer2(
    const int* __restrict__ ego, const int* __restrict__ nodeslot, const int* __restrict__ rowptr,
    const int* __restrict__ src_csr, const float* __restrict__ enorm_csr,
    const float* __restrict__ fni1, const float* __restrict__ fnj1,
    const float* __restrict__ fni3_S, const float* __restrict__ fnj3_S, const float* __restrict__ ft3_S,
    const float* __restrict__ Wfij1, const float* __restrict__ attn1, const float* __restrict__ bias1,
    const float* __restrict__ Wfij3, const float* __restrict__ attn3, const float* __restrict__ bias3,
    float* __restrict__ hG2e)
{
  int lane = threadIdx.x & 63;
  int b = blockIdx.x * (blockDim.x >> 6) + (threadIdx.x >> 6);
  if (b >= N_BATCH) return;
  int n = ego[b];
  int slot = nodeslot[n];
  int j0 = rowptr[slot], j1 = rowptr[slot + 1];
  float wf0 = Wfij1[0], wf1 = Wfij1[1], wf2 = Wfij1[2];
  float at0 = attn1[0], at1 = attn1[1], at2 = attn1[2];
  float b0 = bias1[0], b1 = bias1[1], b2 = bias1[2];
  float g0 = Wfij3[0], g1 = Wfij3[1], g2 = Wfij3[2];
  float at3 = attn3[0], bb3 = bias3[0];
  float fj0 = fnj1[n * 3 + 0], fj1 = fnj1[n * 3 + 1], fj2 = fnj1[n * 3 + 2];
  float fnj3v = fnj3_S[slot];

  float m = -1e30f;
  for (int j = j0 + lane; j < j1; j += 64){
    int sn = src_csr[j]; float en = enorm_csr[j];
    float l0 = lrelu(fni1[sn * 3 + 0] + fj0 + en * wf0 + b0);
    float l1 = lrelu(fni1[sn * 3 + 1] + fj1 + en * wf1 + b1);
    float l2 = lrelu(fni1[sn * 3 + 2] + fj2 + en * wf2 + b2);
    float fe3 = l0 * g0 + l1 * g1 + l2 * g2;
    float l3 = lrelu(fni3_S[nodeslot[sn]] + fnj3v + fe3 + bb3);
    m = fmaxf(m, l3 * at3);
  }
  #pragma unroll
  for (int off = 32; off > 0; off >>= 1) m = fmaxf(m, __shfl_xor(m, off));

  float ssum = 0.f, a0 = 0.f, a1 = 0.f;
  for (int base = j0; base < j1; base += 64){
    int j = base + lane;
    float w = 0.f; int ss = 0;
    if (j < j1){
      int sn = src_csr[j]; float en = enorm_csr[j];
      float l0 = lrelu(fni1[sn * 3 + 0] + fj0 + en * wf0 + b0);
      float l1 = lrelu(fni1[sn * 3 + 1] + fj1 + en * wf1 + b1);
      float l2 = lrelu(fni1[sn * 3 + 2] + fj2 + en * wf2 + b2);
      float fe3 = l0 * g0 + l1 * g1 + l2 * g2;
      ss = nodeslot[sn];
      float l3 = lrelu(fni3_S[ss] + fnj3v + fe3 + bb3);
      w = __expf(l3 * at3 - m);
    }
    int cnt2 = min(64, j1 - base);
    for (int i = 0; i < cnt2; i++){
      float ww = __shfl(w, i); int s2 = __shfl(ss, i);
      ssum += ww;
      a0 += ww * ft3_S[(long long)s2 * 128 + lane];
      a1 += ww * ft3_S[(long long)s2 * 128 + 64 + lane];
    }
  }
  float inv = (j1 > j0) ? 1.f / ssum : 0.f;
  hG2e[b * 128 + lane] = fmaxf(0.f, a0 * inv);
  hG2e[b * 128 + 64 + lane] = fmaxf(0.f, a1 * inv);
}

// ---------------- fused MLPs + fusion + heads ----------------

__device__ __forceinline__ float block_sum_128(float v, float* red, int t){
  red[t] = v; __syncthreads();
  #pragma unroll
  for (int off = 64; off > 0; off >>= 1){
    if (t < off) red[t] += red[t + off];
    __syncthreads();
  }
  float s = red[0]; __syncthreads();
  return s;
}

__device__ __forceinline__ float ln_relu_128(float x, float g, float bb, float* red, int t){
  float mu = block_sum_128(x, red, t) * (1.f / 128.f);
  float d = x - mu;
  float var = block_sum_128(d * d, red, t) * (1.f / 128.f);
  return fmaxf(0.f, d * rsqrtf(var + 1e-5f) * g + bb);
}

__global__ __launch_bounds__(128) void k_mlp(
    const float* __restrict__ sensor, const float* __restrict__ target, const float* __restrict__ area,
    const float* __restrict__ hG2e,
    const float* __restrict__ Ws1, const float* __restrict__ bs1,
    const float* __restrict__ Ws3, const float* __restrict__ bs3,
    const float* __restrict__ Wt1, const float* __restrict__ bt1,
    const float* __restrict__ Wt2, const float* __restrict__ bt2,
    const float* __restrict__ gM, const float* __restrict__ bM,
    const float* __restrict__ gF, const float* __restrict__ bF,
    const float* __restrict__ Wfc, const float* __restrict__ bfc,
    const float* __restrict__ Wst, const float* __restrict__ bst,
    const float* __restrict__ Wca, const float* __restrict__ bca,
    float* __restrict__ out)
{
  int b = blockIdx.x, t = threadIdx.x;
  __shared__ float xin[384];
  __shared__ float v1[128];
  __shared__ float red[128];
  float g_m = gM[t], b_m = bM[t];

  // sensor MLP
  if (t < 64) xin[t] = sensor[b * 64 + t];
  __syncthreads();
  float x = bs1[t];
  #pragma unroll 8
  for (int c = 0; c < 64; c++) x += Ws1[t * 64 + c] * xin[c];
  x = ln_relu_128(x, g_m, b_m, red, t);
  v1[t] = x; __syncthreads();
  float x2 = bs3[t];
  #pragma unroll 8
  for (int c = 0; c < 128; c++) x2 += Ws3[t * 128 + c] * v1[c];
  float hSv = ln_relu_128(x2, g_m, b_m, red, t);
  __syncthreads();

  // target MLP
  if (t < 32) xin[t] = target[b * 32 + t];
  else if (t < 64) xin[t] = area[b * 32 + (t - 32)];
  __syncthreads();
  float y = bt1[t];
  #pragma unroll 8
  for (int c = 0; c < 64; c++) y += Wt1[t * 64 + c] * xin[c];
  y = ln_relu_128(y, g_m, b_m, red, t);
  v1[t] = y; __syncthreads();
  float y2 = bt2[t];
  #pragma unroll 8
  for (int c = 0; c < 128; c++) y2 += Wt2[t * 128 + c] * v1[c];
  float hTv = ln_relu_128(y2, g_m, b_m, red, t);
  __syncthreads();

  // fusion
  xin[t] = hG2e[b * 128 + t];
  xin[128 + t] = hSv;
  xin[256 + t] = hTv;
  __syncthreads();
  float z = bfc[t];
  #pragma unroll 8
  for (int c = 0; c < 384; c++) z += Wfc[t * 384 + c] * xin[c];
  z = ln_relu_128(z, gF[t], bF[t], red, t);
  v1[t] = z; __syncthreads();

  // heads
  if (t < 6){
    float a = bst[t];
    #pragma unroll 8
    for (int c = 0; c < 128; c++) a += Wst[t * 128 + c] * v1[c];
    out[b * 6 + t] = a;
  }
  if (t >= 64 && t < 72){
    int i = t - 64;
    float a = bca[i];
    #pragma unroll 8
    for (int c = 0; c < 128; c++) a += Wca[i * 128 + c] * v1[c];
    out[N_BATCH * 6 + b * 8 + i] = a;
  }
}

// ---------------- host ----------------

extern "C" void kernel_launch(void* const* d_in, const int* in_sizes, int n_in,
                              void* d_out, int out_size, void* d_ws, size_t ws_size,
                              hipStream_t stream)
{
  const float* feat   = (const float*)d_in[0];
  const float* enorm  = (const float*)d_in[1];
  const float* sensor = (const float*)d_in[2];
  const float* target = (const float*)d_in[3];
  const float* area   = (const float*)d_in[4];
  const int*   src    = (const int*)d_in[5];
  const int*   dst    = (const int*)d_in[6];
  const int*   ego    = (const int*)d_in[7];
  const float* Wni1   = (const float*)d_in[8];
  const float* Wnj1   = (const float*)d_in[9];
  const float* Wfij1  = (const float*)d_in[10];
  const float* Wnode1 = (const float*)d_in[11];
  const float* attn1  = (const float*)d_in[12];
  const float* bias1  = (const float*)d_in[13];
  const float* Wni3   = (const float*)d_in[14];
  const float* Wnj3   = (const float*)d_in[15];
  const float* Wfij3  = (const float*)d_in[16];
  const float* Wnode3 = (const float*)d_in[17];
  const float* attn3  = (const float*)d_in[18];
  const float* bias3  = (const float*)d_in[19];
  const float* Ws1    = (const float*)d_in[20];
  const float* bs1    = (const float*)d_in[21];
  const float* Ws3    = (const float*)d_in[22];
  const float* bs3    = (const float*)d_in[23];
  const float* Wt1    = (const float*)d_in[24];
  const float* bt1    = (const float*)d_in[25];
  const float* Wt2    = (const float*)d_in[26];
  const float* bt2    = (const float*)d_in[27];
  const float* gM     = (const float*)d_in[28];
  const float* bM     = (const float*)d_in[29];
  const float* gF     = (const float*)d_in[30];
  const float* bF     = (const float*)d_in[31];
  const float* Wfc    = (const float*)d_in[32];
  const float* bfc    = (const float*)d_in[33];
  const float* Wst    = (const float*)d_in[34];
  const float* bst    = (const float*)d_in[35];
  const float* Wca    = (const float*)d_in[36];
  const float* bca    = (const float*)d_in[37];
  float* out = (float*)d_out;

  char* ws = (char*)d_ws;
  size_t off = 0;
  auto alloc = [&](size_t bytes) -> size_t {
    size_t o = off;
    off = (off + bytes + 255) & ~(size_t)255;
    return o;
  };

  // zero-init region (must be first, contiguous from 0)
  size_t o_meta    = alloc(256);
  size_t o_egoflag = alloc((size_t)N_NODES * 4);
  size_t o_Sflag   = alloc((size_t)N_NODES * 4);
  size_t o_cnt     = alloc((size_t)(N_NODES + 1) * 4);
  size_t o_cursor  = alloc((size_t)N_NODES * 4);
  size_t zero_bytes = off;
  // non-zeroed fixed arrays
  size_t o_fni1    = alloc((size_t)N_NODES * 3 * 4);
  size_t o_fnj1    = alloc((size_t)N_NODES * 3 * 4);
  size_t o_nodeslot= alloc((size_t)N_NODES * 4);
  size_t o_S_ids   = alloc((size_t)N_NODES * 4);
  size_t o_rowptr  = alloc((size_t)(N_NODES + 1) * 4);
  size_t o_fni3    = alloc((size_t)N_NODES * 4);
  size_t o_fnj3    = alloc((size_t)N_NODES * 4);
  size_t o_hG2e    = alloc((size_t)N_BATCH * 128 * 4);
  // dynamic capacity arrays
  size_t rem = (ws_size > off) ? ws_size - off : 0;
  size_t ecap = rem / 40;                       // ~20% to edge arrays (8 B/edge)
  if (ecap > (size_t)N_EDGES) ecap = N_EDGES;
  if (ecap < 1) ecap = 1;
  size_t o_src_csr   = alloc(ecap * 4);
  size_t o_enorm_csr = alloc(ecap * 4);
  size_t rem2 = (ws_size > off) ? ws_size - off : 0;
  size_t scap = rem2 / 1280;                    // 768 B + 512 B per slot
  if (scap > (size_t)N_NODES) scap = N_NODES;
  if (scap < 1) scap = 1;
  size_t o_hG_S  = alloc(scap * 768);
  size_t o_ft3_S = alloc(scap * 512);

  int*   meta      = (int*)(ws + o_meta);
  int*   egoflag   = (int*)(ws + o_egoflag);
  int*   Sflag     = (int*)(ws + o_Sflag);
  int*   cnt       = (int*)(ws + o_cnt);
  int*   cursor    = (int*)(ws + o_cursor);
  float* fni1      = (float*)(ws + o_fni1);
  float* fnj1      = (float*)(ws + o_fnj1);
  int*   nodeslot  = (int*)(ws + o_nodeslot);
  int*   S_ids     = (int*)(ws + o_S_ids);
  int*   rowptr    = (int*)(ws + o_rowptr);
  float* fni3_S    = (float*)(ws + o_fni3);
  float* fnj3_S    = (float*)(ws + o_fnj3);
  float* hG2e      = (float*)(ws + o_hG2e);
  int*   src_csr   = (int*)(ws + o_src_csr);
  float* enorm_csr = (float*)(ws + o_enorm_csr);
  float* hG_S      = (float*)(ws + o_hG_S);
  float* ft3_S     = (float*)(ws + o_ft3_S);

  hipMemsetAsync(ws, 0, zero_bytes, stream);

  k_mark_ego<<<(N_BATCH + 255) / 256, 256, 0, stream>>>(ego, egoflag, Sflag);
  k_node_lin1<<<(N_NODES + 255) / 256, 256, 0, stream>>>(feat, Wni1, Wnj1, fni1, fnj1);
  k_mark_S<<<(N_EDGES + 255) / 256, 256, 0, stream>>>(src, dst, egoflag, Sflag);
  k_compact<<<(N_NODES + 255) / 256, 256, 0, stream>>>(Sflag, nodeslot, S_ids, meta);
  k_count<<<(N_EDGES + 255) / 256, 256, 0, stream>>>(src, dst, Sflag, nodeslot, cnt);
  k_scan<<<1, 1024, 0, stream>>>(cnt, rowptr, meta);
  k_fill<<<(N_EDGES + 255) / 256, 256, 0, stream>>>(src, dst, enorm, Sflag, nodeslot,
                                                    rowptr, cursor, src_csr, enorm_csr);
  k6_layer1<<<1024, 256, 0, stream>>>(feat, fni1, fnj1, S_ids, rowptr, src_csr, enorm_csr,
                                      Wnode1, Wfij1, attn1, bias1, meta, hG_S);
  k6b_ft3<<<1024, 256, 0, stream>>>(hG_S, Wnode3, Wni3, Wnj3, meta, ft3_S, fni3_S, fnj3_S);
  k8_layer2<<<(N_BATCH * 64 + 255) / 256, 256, 0, stream>>>(
      ego, nodeslot, rowptr, src_csr, enorm_csr, fni1, fnj1,
      fni3_S, fnj3_S, ft3_S, Wfij1, attn1, bias1, Wfij3, attn3, bias3, hG2e);
  k_mlp<<<N_BATCH, 128, 0, stream>>>(sensor, target, area, hG2e,
                                     Ws1, bs1, Ws3, bs3, Wt1, bt1, Wt2, bt2,
                                     gM, bM, gF, bF, Wfc, bfc, Wst, bst, Wca, bca, out);
  (void)in_sizes; (void)n_in; (void)out_size;
}

// Round 2
// 386.950 us; speedup vs baseline: 1.0215x; 1.0215x over previous
//
#include <hip/hip_runtime.h>
#include <cstdint>

#define N_NODES 100000
#define N_EDGES 1600000
#define N_BATCH 1000
#define LEAK 0.01f

__device__ __forceinline__ float lrelu(float x){ return x > 0.f ? x : LEAK * x; }

// ---------------- graph preprocessing ----------------

// fused: ego marking + node linear projections (layer-1 f_ni / f_nj)
__global__ void k_pre(const int* __restrict__ ego, int* __restrict__ egoflag, int* __restrict__ Sflag,
                      const float* __restrict__ feat,
                      const float* __restrict__ Wni1, const float* __restrict__ Wnj1,
                      float* __restrict__ fni1, float* __restrict__ fnj1){
  int n = blockIdx.x * blockDim.x + threadIdx.x;
  if (n < N_BATCH){ int e = ego[n]; egoflag[e] = 1; Sflag[e] = 1; }
  if (n >= N_NODES) return;
  const float4* f4 = (const float4*)(feat + (size_t)n * 16);
  float4 a = f4[0], b = f4[1], c = f4[2], d = f4[3];
  float f[16] = {a.x,a.y,a.z,a.w, b.x,b.y,b.z,b.w, c.x,c.y,c.z,c.w, d.x,d.y,d.z,d.w};
  #pragma unroll
  for (int h = 0; h < 3; h++){
    float s0 = 0.f, s1 = 0.f;
    #pragma unroll
    for (int k = 0; k < 16; k++){ s0 += f[k] * Wni1[h * 16 + k]; s1 += f[k] * Wnj1[h * 16 + k]; }
    fni1[n * 3 + h] = s0; fnj1[n * 3 + h] = s1;
  }
}

__global__ void k_mark_S(const int* __restrict__ src, const int* __restrict__ dst,
                         const int* __restrict__ egoflag, int* __restrict__ Sflag){
  int e = blockIdx.x * blockDim.x + threadIdx.x;
  if (e < N_EDGES && egoflag[dst[e]]) Sflag[src[e]] = 1;   // benign race, all write 1
}

__global__ void k_compact(const int* __restrict__ Sflag, int* __restrict__ nodeslot,
                          int* __restrict__ S_ids, int* __restrict__ meta){
  int n = blockIdx.x * blockDim.x + threadIdx.x;
  if (n < N_NODES && Sflag[n]){
    int s = atomicAdd(&meta[0], 1);
    S_ids[s] = n; nodeslot[n] = s;
  }
}

__global__ void k_count(const int* __restrict__ src, const int* __restrict__ dst,
                        const int* __restrict__ Sflag, const int* __restrict__ nodeslot,
                        int* __restrict__ cnt){
  int e = blockIdx.x * blockDim.x + threadIdx.x;
  if (e < N_EDGES && Sflag[dst[e]]) atomicAdd(&cnt[nodeslot[dst[e]]], 1);
}

// single-block scan: serial-per-thread + wave shfl scan (3 barriers total)
__global__ __launch_bounds__(1024) void k_scan(const int* __restrict__ cnt, int* __restrict__ rowptr,
                                               const int* __restrict__ meta){
  __shared__ int wsum[16];
  __shared__ int woff[16];
  const int S = meta[0];
  int t = threadIdx.x, lane = t & 63, w = t >> 6;
  int per = (S + 1023) >> 10;
  int lo = t * per; if (lo > S) lo = S;
  int hi = lo + per; if (hi > S) hi = S;
  int sum = 0;
  for (int i = lo; i < hi; i++) sum += cnt[i];
  int v = sum;
  #pragma unroll
  for (int off = 1; off < 64; off <<= 1){
    int u = __shfl_up(v, off);
    if (lane >= off) v += u;
  }
  if (lane == 63) wsum[w] = v;
  __syncthreads();
  if (t == 0){
    int run = 0;
    for (int k = 0; k < 16; k++){ woff[k] = run; run += wsum[k]; }
    rowptr[S] = run;
  }
  __syncthreads();
  int run = woff[w] + v - sum;     // exclusive prefix at this thread's chunk start
  for (int i = lo; i < hi; i++){ rowptr[i] = run; run += cnt[i]; }
}

__global__ void k_fill(const int* __restrict__ src, const int* __restrict__ dst,
                       const float* __restrict__ enorm,
                       const int* __restrict__ Sflag, const int* __restrict__ nodeslot,
                       const int* __restrict__ rowptr, int* __restrict__ cursor,
                       int* __restrict__ src_csr, float* __restrict__ enorm_csr){
  int e = blockIdx.x * blockDim.x + threadIdx.x;
  if (e < N_EDGES && Sflag[dst[e]]){
    int s = nodeslot[dst[e]];
    int p = rowptr[s] + atomicAdd(&cursor[s], 1);
    src_csr[p] = src[e];
    enorm_csr[p] = enorm[e];
  }
}

// ---------------- layer 1: fused logits + segment softmax + aggregate + Wnode1 (+ni3/nj3) ----------------

__global__ __launch_bounds__(256) void k6_layer1(
    const float* __restrict__ feat, const float* __restrict__ fni1, const float* __restrict__ fnj1,
    const int* __restrict__ S_ids, const int* __restrict__ rowptr,
    const int* __restrict__ src_csr, const float* __restrict__ enorm_csr,
    const float* __restrict__ Wnode1, const float* __restrict__ Wfij1,
    const float* __restrict__ attn1, const float* __restrict__ bias1,
    const float* __restrict__ Wni3, const float* __restrict__ Wnj3,
    const int* __restrict__ meta, float* __restrict__ hG_S,
    float* __restrict__ fni3_S, float* __restrict__ fnj3_S)
{
  __shared__ float Wn1[192 * 17];             // +1 pad per 16-row: bank-conflict free
  for (int i = threadIdx.x; i < 3072; i += 256) Wn1[(i >> 4) * 17 + (i & 15)] = Wnode1[i];
  __syncthreads();
  const int S = meta[0];
  int lane = threadIdx.x & 63;
  int wid = blockIdx.x * (blockDim.x >> 6) + (threadIdx.x >> 6);
  int nw = gridDim.x * (blockDim.x >> 6);
  float wf0 = Wfij1[0], wf1 = Wfij1[1], wf2 = Wfij1[2];
  float at0 = attn1[0], at1 = attn1[1], at2 = attn1[2];
  float b0 = bias1[0], b1 = bias1[1], b2 = bias1[2];
  float wi3a = Wni3[lane], wi3b = Wni3[64 + lane], wi3c = Wni3[128 + lane];
  float wj3a = Wnj3[lane], wj3b = Wnj3[64 + lane], wj3c = Wnj3[128 + lane];
  int hsel = lane >> 4, csel = lane & 15;

  for (int s = wid; s < S; s += nw){
    int n = S_ids[s];
    int j0 = rowptr[s], j1 = rowptr[s + 1];
    float fj0 = fnj1[n * 3 + 0], fj1 = fnj1[n * 3 + 1], fj2 = fnj1[n * 3 + 2];
    // pass A: per-head max of attention logits
    float m0 = -1e30f, m1 = -1e30f, m2 = -1e30f;
    for (int j = j0 + lane; j < j1; j += 64){
      int sn = src_csr[j]; float en = enorm_csr[j];
      float l0 = lrelu(fni1[sn * 3 + 0] + fj0 + en * wf0 + b0);
      float l1 = lrelu(fni1[sn * 3 + 1] + fj1 + en * wf1 + b1);
      float l2 = lrelu(fni1[sn * 3 + 2] + fj2 + en * wf2 + b2);
      m0 = fmaxf(m0, l0 * at0); m1 = fmaxf(m1, l1 * at1); m2 = fmaxf(m2, l2 * at2);
    }
    #pragma unroll
    for (int off = 32; off > 0; off >>= 1){
      m0 = fmaxf(m0, __shfl_xor(m0, off));
      m1 = fmaxf(m1, __shfl_xor(m1, off));
      m2 = fmaxf(m2, __shfl_xor(m2, off));
    }
    // pass B: exp-sum and weighted feat aggregation (lane<48: h=lane/16, c=lane%16)
    float s0 = 0.f, s1 = 0.f, s2 = 0.f, wsum = 0.f;
    for (int base = j0; base < j1; base += 64){
      int j = base + lane;
      float w0 = 0.f, w1 = 0.f, w2 = 0.f; int sn = 0;
      if (j < j1){
        sn = src_csr[j]; float en = enorm_csr[j];
        float l0 = lrelu(fni1[sn * 3 + 0] + fj0 + en * wf0 + b0);
        float l1 = lrelu(fni1[sn * 3 + 1] + fj1 + en * wf1 + b1);
        float l2 = lrelu(fni1[sn * 3 + 2] + fj2 + en * wf2 + b2);
        w0 = __expf(l0 * at0 - m0); w1 = __expf(l1 * at1 - m1); w2 = __expf(l2 * at2 - m2);
      }
      int cnt2 = min(64, j1 - base);
      for (int i = 0; i < cnt2; i++){
        float ww0 = __shfl(w0, i), ww1 = __shfl(w1, i), ww2 = __shfl(w2, i);
        int ssn = __shfl(sn, i);
        s0 += ww0; s1 += ww1; s2 += ww2;
        if (lane < 48){
          float f = feat[ssn * 16 + csel];
          float wh = hsel == 0 ? ww0 : (hsel == 1 ? ww1 : ww2);
          wsum += wh * f;
        }
      }
    }
    float aval = 0.f;
    if (lane < 48 && j1 > j0){
      float sh = hsel == 0 ? s0 : (hsel == 1 ? s1 : s2);
      aval = wsum / sh;
    }
    // epilogue: hG[n, h*64+o] = relu( a[h,:] . Wnode1[h*64+o,:] ), plus ni3/nj3 dots
    float hv[3];
    #pragma unroll
    for (int r = 0; r < 3; r++){
      float acc = 0.f;
      #pragma unroll
      for (int c = 0; c < 16; c++)
        acc += __shfl(aval, r * 16 + c) * Wn1[(r * 64 + lane) * 17 + c];
      hv[r] = fmaxf(acc, 0.f);
      hG_S[(long long)s * 192 + r * 64 + lane] = hv[r];
    }
    float ni = hv[0] * wi3a + hv[1] * wi3b + hv[2] * wi3c;
    float nj = hv[0] * wj3a + hv[1] * wj3b + hv[2] * wj3c;
    #pragma unroll
    for (int off = 32; off > 0; off >>= 1){
      ni += __shfl_xor(ni, off);
      nj += __shfl_xor(nj, off);
    }
    if (lane == 0){ fni3_S[s] = ni; fnj3_S[s] = nj; }
  }
}

// ---------------- ft3 = hG_S @ Wnode3^T : LDS-tiled fp32 GEMM ----------------

#define K6B_RT 32

__global__ __launch_bounds__(256) void k6b_ft3(
    const float* __restrict__ hG_S, const float* __restrict__ Wnode3,
    const int* __restrict__ meta, float* __restrict__ ft3_S)
{
  __shared__ float Wl[96 * 129];                      // 49.5 KB: 96-col chunk, transposed, pad 129
  __shared__ __align__(16) float hl[K6B_RT * 196];    // 25 KB: 32 rows, pad 196 (float4-aligned)
  const int S = meta[0];
  const int t = threadIdx.x;
  const int o2 = t & 63, rg = t >> 6;                 // wave = row-group of 8
  int ntiles = (S + K6B_RT - 1) / K6B_RT;
  for (int tile = blockIdx.x; tile < ntiles; tile += gridDim.x){
    __syncthreads();                                  // protect hl/Wl reuse across tiles
    int row0 = tile * K6B_RT;
    int nrows = min(K6B_RT, S - row0);
    for (int i = t; i < K6B_RT * 192; i += 256){
      int r = i / 192, c = i - r * 192;
      hl[r * 196 + c] = (r < nrows) ? hG_S[(long long)(row0 + r) * 192 + c] : 0.f;
    }
    float acc[8][2];
    #pragma unroll
    for (int r = 0; r < 8; r++){ acc[r][0] = 0.f; acc[r][1] = 0.f; }
    for (int ch = 0; ch < 2; ch++){
      __syncthreads();                                // hl ready (ch=0) / Wl free (ch=1)
      for (int i = t; i < 96 * 128; i += 256){
        int o = i / 96, cl = i - o * 96;              // consecutive i -> consecutive global c
        Wl[cl * 129 + o] = Wnode3[o * 192 + ch * 96 + cl];
      }
      __syncthreads();
      #pragma unroll 4
      for (int c4 = 0; c4 < 24; c4++){
        float w0[4], w1[4];
        #pragma unroll
        for (int j = 0; j < 4; j++){
          w0[j] = Wl[(c4 * 4 + j) * 129 + o2];
          w1[j] = Wl[(c4 * 4 + j) * 129 + o2 + 64];
        }
        #pragma unroll
        for (int r = 0; r < 8; r++){
          const float4 h4 = *(const float4*)&hl[(rg * 8 + r) * 196 + ch * 96 + c4 * 4];
          acc[r][0] += h4.x * w0[0] + h4.y * w0[1] + h4.z * w0[2] + h4.w * w0[3];
          acc[r][1] += h4.x * w1[0] + h4.y * w1[1] + h4.z * w1[2] + h4.w * w1[3];
        }
      }
    }
    #pragma unroll
    for (int r = 0; r < 8; r++){
      int rr = rg * 8 + r;
      if (rr < nrows){
        ft3_S[(long long)(row0 + rr) * 128 + o2] = acc[r][0];
        ft3_S[(long long)(row0 + rr) * 128 + 64 + o2] = acc[r][1];
      }
    }
  }
}

// ---------------- layer 2 (ego nodes only) ----------------

__global__ __launch_bounds__(256) void k8_layer2(
    const int* __restrict__ ego, const int* __restrict__ nodeslot, const int* __restrict__ rowptr,
    const int* __restrict__ src_csr, const float* __restrict__ enorm_csr,
    const float* __restrict__ fni1, const float* __restrict__ fnj1,
    const float* __restrict__ fni3_S, const float* __restrict__ fnj3_S, const float* __restrict__ ft3_S,
    const float* __restrict__ Wfij1, const float* __restrict__ attn1, const float* __restrict__ bias1,
    const float* __restrict__ Wfij3, const float* __restrict__ attn3, const float* __restrict__ bias3,
    float* __restrict__ hG2e)
{
  int lane = threadIdx.x & 63;
  int b = blockIdx.x * (blockDim.x >> 6) + (threadIdx.x >> 6);
  if (b >= N_BATCH) return;
  int n = ego[b];
  int slot = nodeslot[n];
  int j0 = rowptr[slot], j1 = rowptr[slot + 1];
  float wf0 = Wfij1[0], wf1 = Wfij1[1], wf2 = Wfij1[2];
  float at0 = attn1[0], at1 = attn1[1], at2 = attn1[2];
  float b0 = bias1[0], b1 = bias1[1], b2 = bias1[2];
  float g0 = Wfij3[0], g1 = Wfij3[1], g2 = Wfij3[2];
  float at3 = attn3[0], bb3 = bias3[0];
  float fj0 = fnj1[n * 3 + 0], fj1 = fnj1[n * 3 + 1], fj2 = fnj1[n * 3 + 2];
  float fnj3v = fnj3_S[slot];

  float m = -1e30f;
  for (int j = j0 + lane; j < j1; j += 64){
    int sn = src_csr[j]; float en = enorm_csr[j];
    float l0 = lrelu(fni1[sn * 3 + 0] + fj0 + en * wf0 + b0);
    float l1 = lrelu(fni1[sn * 3 + 1] + fj1 + en * wf1 + b1);
    float l2 = lrelu(fni1[sn * 3 + 2] + fj2 + en * wf2 + b2);
    float fe3 = l0 * g0 + l1 * g1 + l2 * g2;
    float l3 = lrelu(fni3_S[nodeslot[sn]] + fnj3v + fe3 + bb3);
    m = fmaxf(m, l3 * at3);
  }
  #pragma unroll
  for (int off = 32; off > 0; off >>= 1) m = fmaxf(m, __shfl_xor(m, off));

  float ssum = 0.f, a0 = 0.f, a1 = 0.f;
  for (int base = j0; base < j1; base += 64){
    int j = base + lane;
    float w = 0.f; int ss = 0;
    if (j < j1){
      int sn = src_csr[j]; float en = enorm_csr[j];
      float l0 = lrelu(fni1[sn * 3 + 0] + fj0 + en * wf0 + b0);
      float l1 = lrelu(fni1[sn * 3 + 1] + fj1 + en * wf1 + b1);
      float l2 = lrelu(fni1[sn * 3 + 2] + fj2 + en * wf2 + b2);
      float fe3 = l0 * g0 + l1 * g1 + l2 * g2;
      ss = nodeslot[sn];
      float l3 = lrelu(fni3_S[ss] + fnj3v + fe3 + bb3);
      w = __expf(l3 * at3 - m);
    }
    int cnt2 = min(64, j1 - base);
    for (int i = 0; i < cnt2; i++){
      float ww = __shfl(w, i); int s2 = __shfl(ss, i);
      ssum += ww;
      a0 += ww * ft3_S[(long long)s2 * 128 + lane];
      a1 += ww * ft3_S[(long long)s2 * 128 + 64 + lane];
    }
  }
  float inv = (j1 > j0) ? 1.f / ssum : 0.f;
  hG2e[b * 128 + lane] = fmaxf(0.f, a0 * inv);
  hG2e[b * 128 + 64 + lane] = fmaxf(0.f, a1 * inv);
}

// ---------------- fused MLPs + fusion + heads (LDS-staged weights) ----------------

// per-128-group sums of two values via wave shfl + 8-slot LDS combine
__device__ __forceinline__ void grp_sums2(float v0, float v1, float* red, int t, float& s0, float& s1){
  float a0 = v0, a1 = v1;
  #pragma unroll
  for (int off = 32; off > 0; off >>= 1){
    a0 += __shfl_xor(a0, off);
    a1 += __shfl_xor(a1, off);
  }
  int w = t >> 6;
  if ((t & 63) == 0){ red[w * 2] = a0; red[w * 2 + 1] = a1; }
  __syncthreads();
  int rg = t >> 7;
  s0 = red[rg * 4 + 0] + red[rg * 4 + 2];
  s1 = red[rg * 4 + 1] + red[rg * 4 + 3];
  __syncthreads();
}

__device__ __forceinline__ void ln_relu2(float& z0, float& z1, float g, float bb, float* red, int t){
  float s0, s1;
  grp_sums2(z0, z1, red, t, s0, s1);
  float d0 = z0 - s0 * (1.f / 128.f), d1 = z1 - s1 * (1.f / 128.f);
  float q0, q1;
  grp_sums2(d0 * d0, d1 * d1, red, t, q0, q1);
  z0 = fmaxf(0.f, d0 * rsqrtf(q0 * (1.f / 128.f) + 1e-5f) * g + bb);
  z1 = fmaxf(0.f, d1 * rsqrtf(q1 * (1.f / 128.f) + 1e-5f) * g + bb);
}

template<int K>
__device__ __forceinline__ void stageW(const float* __restrict__ Wg, float* Wl, int t){
  for (int i = t; i < 128 * K; i += 256){
    int oo = i / K, cc = i - oo * K;
    Wl[cc * 129 + oo] = Wg[i];                        // coalesced read, bank-stride-1 write
  }
}

__global__ __launch_bounds__(256) void k_mlp(
    const float* __restrict__ sensor, const float* __restrict__ target, const float* __restrict__ area,
    const float* __restrict__ hG2e,
    const float* __restrict__ Ws1, const float* __restrict__ bs1,
    const float* __restrict__ Ws3, const float* __restrict__ bs3,
    const float* __restrict__ Wt1, const float* __restrict__ bt1,
    const float* __restrict__ Wt2, const float* __restrict__ bt2,
    const float* __restrict__ gM, const float* __restrict__ bM,
    const float* __restrict__ gF, const float* __restrict__ bF,
    const float* __restrict__ Wfc, const float* __restrict__ bfc,
    const float* __restrict__ Wst, const float* __restrict__ bst,
    const float* __restrict__ Wca, const float* __restrict__ bca,
    float* __restrict__ out)
{
  __shared__ float Wl[192 * 129];      // 99 KB
  __shared__ float bufA[4 * 128];
  __shared__ float bufB[4 * 128];
  __shared__ float xc[4 * 384];        // fusion input [hG2e | hS | hT]
  __shared__ float red[8];
  const int t = threadIdx.x;
  const int b0 = blockIdx.x * 4;
  const int o = t & 127, rg = t >> 7;
  const int r0 = rg * 2, r1 = rg * 2 + 1;
  float g_m = gM[o], b_m = bM[o];

  // load sensor rows + hG2e rows
  for (int i = t; i < 256; i += 256){
    int r = i >> 6, c = i & 63;
    bufA[r * 128 + c] = sensor[(b0 + r) * 64 + c];
  }
  for (int i = t; i < 512; i += 256){
    int r = i >> 7, c = i & 127;
    xc[r * 384 + c] = hG2e[(b0 + r) * 128 + c];
  }
  stageW<64>(Ws1, Wl, t);
  __syncthreads();

  // sensor layer 1 (K=64)
  float z0 = bs1[o], z1 = z0;
  #pragma unroll 8
  for (int c = 0; c < 64; c++){
    float w = Wl[c * 129 + o];
    z0 += w * bufA[r0 * 128 + c];
    z1 += w * bufA[r1 * 128 + c];
  }
  ln_relu2(z0, z1, g_m, b_m, red, t);
  bufB[r0 * 128 + o] = z0; bufB[r1 * 128 + o] = z1;
  __syncthreads();
  stageW<128>(Ws3, Wl, t);
  __syncthreads();

  // sensor layer 2 (K=128) -> xc[:,128..256)
  z0 = bs3[o]; z1 = z0;
  #pragma unroll 8
  for (int c = 0; c < 128; c++){
    float w = Wl[c * 129 + o];
    z0 += w * bufB[r0 * 128 + c];
    z1 += w * bufB[r1 * 128 + c];
  }
  ln_relu2(z0, z1, g_m, b_m, red, t);
  xc[r0 * 384 + 128 + o] = z0; xc[r1 * 384 + 128 + o] = z1;

  // load target|area rows
  for (int i = t; i < 256; i += 256){
    int r = i >> 6, c = i & 63;
    bufA[r * 128 + c] = (c < 32) ? target[(b0 + r) * 32 + c] : area[(b0 + r) * 32 + c - 32];
  }
  __syncthreads();
  stageW<64>(Wt1, Wl, t);
  __syncthreads();

  // target layer 1 (K=64)
  z0 = bt1[o]; z1 = z0;
  #pragma unroll 8
  for (int c = 0; c < 64; c++){
    float w = Wl[c * 129 + o];
    z0 += w * bufA[r0 * 128 + c];
    z1 += w * bufA[r1 * 128 + c];
  }
  ln_relu2(z0, z1, g_m, b_m, red, t);
  bufB[r0 * 128 + o] = z0; bufB[r1 * 128 + o] = z1;
  __syncthreads();
  stageW<128>(Wt2, Wl, t);
  __syncthreads();

  // target layer 2 (K=128) -> xc[:,256..384)
  z0 = bt2[o]; z1 = z0;
  #pragma unroll 8
  for (int c = 0; c < 128; c++){
    float w = Wl[c * 129 + o];
    z0 += w * bufB[r0 * 128 + c];
    z1 += w * bufB[r1 * 128 + c];
  }
  ln_relu2(z0, z1, g_m, b_m, red, t);
  xc[r0 * 384 + 256 + o] = z0; xc[r1 * 384 + 256 + o] = z1;
  __syncthreads();

  // fusion (K=384, 2 chunks of 192)
  float f0 = bfc[o], f1 = f0;
  for (int ch = 0; ch < 2; ch++){
    for (int i = t; i < 128 * 192; i += 256){
      int oo = i / 192, cc = i - oo * 192;
      Wl[cc * 129 + oo] = Wfc[oo * 384 + ch * 192 + cc];
    }
    __syncthreads();
    #pragma unroll 8
    for (int c = 0; c < 192; c++){
      float w = Wl[c * 129 + o];
      f0 += w * xc[r0 * 384 + ch * 192 + c];
      f1 += w * xc[r1 * 384 + ch * 192 + c];
    }
    __syncthreads();
  }
  ln_relu2(f0, f1, gF[o], bF[o], red, t);
  bufB[r0 * 128 + o] = f0; bufB[r1 * 128 + o] = f1;
  __syncthreads();

  // heads: stage Wst(6x128)+Wca(8x128) as [c*15 + oh]
  for (int i = t; i < 14 * 128; i += 256){
    int oo = i >> 7, cc = i & 127;
    Wl[cc * 15 + oo] = (oo < 6) ? Wst[oo * 128 + cc] : Wca[(oo - 6) * 128 + cc];
  }
  __syncthreads();
  if (o < 14){
    float a0 = (o < 6) ? bst[o] : bca[o - 6];
    float a1 = a0;
    #pragma unroll 8
    for (int c = 0; c < 128; c++){
      float w = Wl[c * 15 + o];
      a0 += w * bufB[r0 * 128 + c];
      a1 += w * bufB[r1 * 128 + c];
    }
    if (o < 6){
      out[(b0 + r0) * 6 + o] = a0;
      out[(b0 + r1) * 6 + o] = a1;
    } else {
      out[N_BATCH * 6 + (b0 + r0) * 8 + o - 6] = a0;
      out[N_BATCH * 6 + (b0 + r1) * 8 + o - 6] = a1;
    }
  }
}

// ---------------- host ----------------

extern "C" void kernel_launch(void* const* d_in, const int* in_sizes, int n_in,
                              void* d_out, int out_size, void* d_ws, size_t ws_size,
                              hipStream_t stream)
{
  const float* feat   = (const float*)d_in[0];
  const float* enorm  = (const float*)d_in[1];
  const float* sensor = (const float*)d_in[2];
  const float* target = (const float*)d_in[3];
  const float* area   = (const float*)d_in[4];
  const int*   src    = (const int*)d_in[5];
  const int*   dst    = (const int*)d_in[6];
  const int*   ego    = (const int*)d_in[7];
  const float* Wni1   = (const float*)d_in[8];
  const float* Wnj1   = (const float*)d_in[9];
  const float* Wfij1  = (const float*)d_in[10];
  const float* Wnode1 = (const float*)d_in[11];
  const float* attn1  = (const float*)d_in[12];
  const float* bias1  = (const float*)d_in[13];
  const float* Wni3   = (const float*)d_in[14];
  const float* Wnj3   = (const float*)d_in[15];
  const float* Wfij3  = (const float*)d_in[16];
  const float* Wnode3 = (const float*)d_in[17];
  const float* attn3  = (const float*)d_in[18];
  const float* bias3  = (const float*)d_in[19];
  const float* Ws1    = (const float*)d_in[20];
  const float* bs1    = (const float*)d_in[21];
  const float* Ws3    = (const float*)d_in[22];
  const float* bs3    = (const float*)d_in[23];
  const float* Wt1    = (const float*)d_in[24];
  const float* bt1    = (const float*)d_in[25];
  const float* Wt2    = (const float*)d_in[26];
  const float* bt2    = (const float*)d_in[27];
  const float* gM     = (const float*)d_in[28];
  const float* bM     = (const float*)d_in[29];
  const float* gF     = (const float*)d_in[30];
  const float* bF     = (const float*)d_in[31];
  const float* Wfc    = (const float*)d_in[32];
  const float* bfc    = (const float*)d_in[33];
  const float* Wst    = (const float*)d_in[34];
  const float* bst    = (const float*)d_in[35];
  const float* Wca    = (const float*)d_in[36];
  const float* bca    = (const float*)d_in[37];
  float* out = (float*)d_out;

  char* ws = (char*)d_ws;
  size_t off = 0;
  auto alloc = [&](size_t bytes) -> size_t {
    size_t o = off;
    off = (off + bytes + 255) & ~(size_t)255;
    return o;
  };

  // zero-init region (must be first, contiguous from 0)
  size_t o_meta    = alloc(256);
  size_t o_egoflag = alloc((size_t)N_NODES * 4);
  size_t o_Sflag   = alloc((size_t)N_NODES * 4);
  size_t o_cnt     = alloc((size_t)(N_NODES + 1) * 4);
  size_t o_cursor  = alloc((size_t)N_NODES * 4);
  size_t zero_bytes = off;
  // non-zeroed fixed arrays
  size_t o_fni1    = alloc((size_t)N_NODES * 3 * 4);
  size_t o_fnj1    = alloc((size_t)N_NODES * 3 * 4);
  size_t o_nodeslot= alloc((size_t)N_NODES * 4);
  size_t o_S_ids   = alloc((size_t)N_NODES * 4);
  size_t o_rowptr  = alloc((size_t)(N_NODES + 1) * 4);
  size_t o_fni3    = alloc((size_t)N_NODES * 4);
  size_t o_fnj3    = alloc((size_t)N_NODES * 4);
  size_t o_hG2e    = alloc((size_t)N_BATCH * 128 * 4);
  // dynamic capacity arrays
  size_t rem = (ws_size > off) ? ws_size - off : 0;
  size_t ecap = rem / 40;                       // ~20% to edge arrays (8 B/edge)
  if (ecap > (size_t)N_EDGES) ecap = N_EDGES;
  if (ecap < 1) ecap = 1;
  size_t o_src_csr   = alloc(ecap * 4);
  size_t o_enorm_csr = alloc(ecap * 4);
  size_t rem2 = (ws_size > off) ? ws_size - off : 0;
  size_t scap = rem2 / 1280;                    // 768 B + 512 B per slot
  if (scap > (size_t)N_NODES) scap = N_NODES;
  if (scap < 1) scap = 1;
  size_t o_hG_S  = alloc(scap * 768);
  size_t o_ft3_S = alloc(scap * 512);

  int*   meta      = (int*)(ws + o_meta);
  int*   egoflag   = (int*)(ws + o_egoflag);
  int*   Sflag     = (int*)(ws + o_Sflag);
  int*   cnt       = (int*)(ws + o_cnt);
  int*   cursor    = (int*)(ws + o_cursor);
  float* fni1      = (float*)(ws + o_fni1);
  float* fnj1      = (float*)(ws + o_fnj1);
  int*   nodeslot  = (int*)(ws + o_nodeslot);
  int*   S_ids     = (int*)(ws + o_S_ids);
  int*   rowptr    = (int*)(ws + o_rowptr);
  float* fni3_S    = (float*)(ws + o_fni3);
  float* fnj3_S    = (float*)(ws + o_fnj3);
  float* hG2e      = (float*)(ws + o_hG2e);
  int*   src_csr   = (int*)(ws + o_src_csr);
  float* enorm_csr = (float*)(ws + o_enorm_csr);
  float* hG_S      = (float*)(ws + o_hG_S);
  float* ft3_S     = (float*)(ws + o_ft3_S);

  hipMemsetAsync(ws, 0, zero_bytes, stream);

  k_pre<<<(N_NODES + 255) / 256, 256, 0, stream>>>(ego, egoflag, Sflag, feat, Wni1, Wnj1, fni1, fnj1);
  k_mark_S<<<(N_EDGES + 255) / 256, 256, 0, stream>>>(src, dst, egoflag, Sflag);
  k_compact<<<(N_NODES + 255) / 256, 256, 0, stream>>>(Sflag, nodeslot, S_ids, meta);
  k_count<<<(N_EDGES + 255) / 256, 256, 0, stream>>>(src, dst, Sflag, nodeslot, cnt);
  k_scan<<<1, 1024, 0, stream>>>(cnt, rowptr, meta);
  k_fill<<<(N_EDGES + 255) / 256, 256, 0, stream>>>(src, dst, enorm, Sflag, nodeslot,
                                                    rowptr, cursor, src_csr, enorm_csr);
  k6_layer1<<<1024, 256, 0, stream>>>(feat, fni1, fnj1, S_ids, rowptr, src_csr, enorm_csr,
                                      Wnode1, Wfij1, attn1, bias1, Wni3, Wnj3, meta,
                                      hG_S, fni3_S, fnj3_S);
  k6b_ft3<<<1024, 256, 0, stream>>>(hG_S, Wnode3, meta, ft3_S);
  k8_layer2<<<(N_BATCH * 64 + 255) / 256, 256, 0, stream>>>(
      ego, nodeslot, rowptr, src_csr, enorm_csr, fni1, fnj1,
      fni3_S, fnj3_S, ft3_S, Wfij1, attn1, bias1, Wfij3, attn3, bias3, hG2e);
  k_mlp<<<N_BATCH / 4, 256, 0, stream>>>(sensor, target, area, hG2e,
                                         Ws1, bs1, Ws3, bs3, Wt1, bt1, Wt2, bt2,
                                         gM, bM, gF, bF, Wfc, bfc, Wst, bst, Wca, bca, out);
  (void)in_sizes; (void)n_in; (void)out_size;
}

// Round 3
// 326.510 us; speedup vs baseline: 1.2106x; 1.1851x over previous
//
#include <hip/hip_runtime.h>
#include <cstdint>

#define N_NODES 100000
#define N_EDGES 1600000
#define N_BATCH 1000
#define LEAK 0.01f

__device__ __forceinline__ float lrelu(float x){ return x > 0.f ? x : LEAK * x; }
__device__ __forceinline__ float expw(float x){ return __expf(fminf(x, 80.f)); }

// ---------------- graph preprocessing ----------------

// fused: ego marking + node linear projections (layer-1 f_ni / f_nj)
__global__ void k_pre(const int* __restrict__ ego, int* __restrict__ egoflag, int* __restrict__ Sflag,
                      const float* __restrict__ feat,
                      const float* __restrict__ Wni1, const float* __restrict__ Wnj1,
                      float* __restrict__ fni1, float* __restrict__ fnj1){
  int n = blockIdx.x * blockDim.x + threadIdx.x;
  if (n < N_BATCH){ int e = ego[n]; egoflag[e] = 1; Sflag[e] = 1; }
  if (n >= N_NODES) return;
  const float4* f4 = (const float4*)(feat + (size_t)n * 16);
  float4 a = f4[0], b = f4[1], c = f4[2], d = f4[3];
  float f[16] = {a.x,a.y,a.z,a.w, b.x,b.y,b.z,b.w, c.x,c.y,c.z,c.w, d.x,d.y,d.z,d.w};
  #pragma unroll
  for (int h = 0; h < 3; h++){
    float s0 = 0.f, s1 = 0.f;
    #pragma unroll
    for (int k = 0; k < 16; k++){ s0 += f[k] * Wni1[h * 16 + k]; s1 += f[k] * Wnj1[h * 16 + k]; }
    fni1[n * 3 + h] = s0; fnj1[n * 3 + h] = s1;
  }
}

__global__ void k_mark_S(const int* __restrict__ src, const int* __restrict__ dst,
                         const int* __restrict__ egoflag, int* __restrict__ Sflag){
  int e4 = blockIdx.x * blockDim.x + threadIdx.x;
  if (e4 >= N_EDGES / 4) return;
  int4 d = ((const int4*)dst)[e4];
  int f0 = egoflag[d.x], f1 = egoflag[d.y], f2 = egoflag[d.z], f3 = egoflag[d.w];
  if (f0 | f1 | f2 | f3){
    int4 s = ((const int4*)src)[e4];
    if (f0) Sflag[s.x] = 1;
    if (f1) Sflag[s.y] = 1;
    if (f2) Sflag[s.z] = 1;
    if (f3) Sflag[s.w] = 1;
  }
}

__global__ void k_compact(const int* __restrict__ Sflag, int* __restrict__ nodeslot,
                          int* __restrict__ S_ids, int* __restrict__ meta){
  int n = blockIdx.x * blockDim.x + threadIdx.x;
  if (n < N_NODES && Sflag[n]){
    int s = atomicAdd(&meta[0], 1);
    S_ids[s] = n; nodeslot[n] = s;
  }
}

__global__ void k_count(const int* __restrict__ src, const int* __restrict__ dst,
                        const int* __restrict__ Sflag, const int* __restrict__ nodeslot,
                        int* __restrict__ cnt){
  int e4 = blockIdx.x * blockDim.x + threadIdx.x;
  if (e4 >= N_EDGES / 4) return;
  int4 d = ((const int4*)dst)[e4];
  if (Sflag[d.x]) atomicAdd(&cnt[nodeslot[d.x]], 1);
  if (Sflag[d.y]) atomicAdd(&cnt[nodeslot[d.y]], 1);
  if (Sflag[d.z]) atomicAdd(&cnt[nodeslot[d.z]], 1);
  if (Sflag[d.w]) atomicAdd(&cnt[nodeslot[d.w]], 1);
}

// single-block scan: serial-per-thread + wave shfl scan (3 barriers total)
__global__ __launch_bounds__(1024) void k_scan(const int* __restrict__ cnt, int* __restrict__ rowptr,
                                               const int* __restrict__ meta){
  __shared__ int wsum[16];
  __shared__ int woff[16];
  const int S = meta[0];
  int t = threadIdx.x, lane = t & 63, w = t >> 6;
  int per = (S + 1023) >> 10;
  int lo = t * per; if (lo > S) lo = S;
  int hi = lo + per; if (hi > S) hi = S;
  int sum = 0;
  for (int i = lo; i < hi; i++) sum += cnt[i];
  int v = sum;
  #pragma unroll
  for (int off = 1; off < 64; off <<= 1){
    int u = __shfl_up(v, off);
    if (lane >= off) v += u;
  }
  if (lane == 63) wsum[w] = v;
  __syncthreads();
  if (t == 0){
    int run = 0;
    for (int k = 0; k < 16; k++){ woff[k] = run; run += wsum[k]; }
    rowptr[S] = run;
  }
  __syncthreads();
  int run = woff[w] + v - sum;     // exclusive prefix at this thread's chunk start
  for (int i = lo; i < hi; i++){ rowptr[i] = run; run += cnt[i]; }
}

__global__ void k_fill(const int* __restrict__ src, const int* __restrict__ dst,
                       const float* __restrict__ enorm,
                       const int* __restrict__ Sflag, const int* __restrict__ nodeslot,
                       const int* __restrict__ rowptr, int* __restrict__ cursor,
                       int* __restrict__ src_csr, float* __restrict__ enorm_csr){
  int e4 = blockIdx.x * blockDim.x + threadIdx.x;
  if (e4 >= N_EDGES / 4) return;
  int4 d = ((const int4*)dst)[e4];
  int4 s = ((const int4*)src)[e4];
  float4 en = ((const float4*)enorm)[e4];
  int dd[4] = {d.x, d.y, d.z, d.w};
  int ss[4] = {s.x, s.y, s.z, s.w};
  float ee[4] = {en.x, en.y, en.z, en.w};
  #pragma unroll
  for (int u = 0; u < 4; u++){
    if (Sflag[dd[u]]){
      int sl = nodeslot[dd[u]];
      int p = rowptr[sl] + atomicAdd(&cursor[sl], 1);
      src_csr[p] = ss[u];
      enorm_csr[p] = ee[u];
    }
  }
}

// ---------------- layer 1: single-pass softmax (clamped exp) + aggregate + Wnode1 (+ni3/nj3) ----------------

__global__ __launch_bounds__(256) void k6_layer1(
    const float* __restrict__ feat, const float* __restrict__ fni1, const float* __restrict__ fnj1,
    const int* __restrict__ S_ids, const int* __restrict__ rowptr,
    const int* __restrict__ src_csr, const float* __restrict__ enorm_csr,
    const float* __restrict__ Wnode1, const float* __restrict__ Wfij1,
    const float* __restrict__ attn1, const float* __restrict__ bias1,
    const float* __restrict__ Wni3, const float* __restrict__ Wnj3,
    const int* __restrict__ meta, float* __restrict__ hG_S,
    float* __restrict__ fni3_S, float* __restrict__ fnj3_S)
{
  __shared__ float Wn1[192 * 17];             // +1 pad per 16-row: bank-conflict free
  for (int i = threadIdx.x; i < 3072; i += 256) Wn1[(i >> 4) * 17 + (i & 15)] = Wnode1[i];
  __syncthreads();
  const int S = meta[0];
  int lane = threadIdx.x & 63;
  int wid = blockIdx.x * (blockDim.x >> 6) + (threadIdx.x >> 6);
  int nw = gridDim.x * (blockDim.x >> 6);
  float wf0 = Wfij1[0], wf1 = Wfij1[1], wf2 = Wfij1[2];
  float at0 = attn1[0], at1 = attn1[1], at2 = attn1[2];
  float b0 = bias1[0], b1 = bias1[1], b2 = bias1[2];
  float wi3a = Wni3[lane], wi3b = Wni3[64 + lane], wi3c = Wni3[128 + lane];
  float wj3a = Wnj3[lane], wj3b = Wnj3[64 + lane], wj3c = Wnj3[128 + lane];
  int hsel = lane >> 4, csel = lane & 15;

  for (int s = wid; s < S; s += nw){
    int n = S_ids[s];
    int j0 = rowptr[s], j1 = rowptr[s + 1];
    float fj0 = fnj1[n * 3 + 0], fj1 = fnj1[n * 3 + 1], fj2 = fnj1[n * 3 + 2];
    float ls0 = 0.f, ls1 = 0.f, ls2 = 0.f, wsum = 0.f;
    for (int base = j0; base < j1; base += 64){
      int j = base + lane;
      float w0 = 0.f, w1 = 0.f, w2 = 0.f; int sn = 0;
      if (j < j1){
        sn = src_csr[j]; float en = enorm_csr[j];
        float l0 = lrelu(fni1[sn * 3 + 0] + fj0 + en * wf0 + b0);
        float l1 = lrelu(fni1[sn * 3 + 1] + fj1 + en * wf1 + b1);
        float l2 = lrelu(fni1[sn * 3 + 2] + fj2 + en * wf2 + b2);
        w0 = expw(l0 * at0); w1 = expw(l1 * at1); w2 = expw(l2 * at2);
        ls0 += w0; ls1 += w1; ls2 += w2;
      }
      int c2 = min(64, j1 - base);
      for (int i0 = 0; i0 < c2; i0 += 4){
        float fv[4], wv[4];
        #pragma unroll
        for (int u = 0; u < 4; u++){
          int idx = i0 + u;
          int ssn = __shfl(sn, idx);
          float ww0 = __shfl(w0, idx), ww1 = __shfl(w1, idx), ww2 = __shfl(w2, idx);
          wv[u] = hsel == 0 ? ww0 : (hsel == 1 ? ww1 : ww2);
          fv[u] = (idx < c2 && lane < 48) ? feat[ssn * 16 + csel] : 0.f;
        }
        #pragma unroll
        for (int u = 0; u < 4; u++) wsum += wv[u] * fv[u];
      }
    }
    // reduce per-lane exp-sums across the wave
    #pragma unroll
    for (int off = 32; off > 0; off >>= 1){
      ls0 += __shfl_xor(ls0, off);
      ls1 += __shfl_xor(ls1, off);
      ls2 += __shfl_xor(ls2, off);
    }
    float aval = 0.f;
    if (lane < 48 && j1 > j0){
      float sh = hsel == 0 ? ls0 : (hsel == 1 ? ls1 : ls2);
      aval = wsum / sh;
    }
    // epilogue: hG[n, h*64+o] = relu( a[h,:] . Wnode1[h*64+o,:] ), plus ni3/nj3 dots
    float hv[3];
    #pragma unroll
    for (int r = 0; r < 3; r++){
      float acc = 0.f;
      #pragma unroll
      for (int c = 0; c < 16; c++)
        acc += __shfl(aval, r * 16 + c) * Wn1[(r * 64 + lane) * 17 + c];
      hv[r] = fmaxf(acc, 0.f);
      hG_S[(long long)s * 192 + r * 64 + lane] = hv[r];
    }
    float ni = hv[0] * wi3a + hv[1] * wi3b + hv[2] * wi3c;
    float nj = hv[0] * wj3a + hv[1] * wj3b + hv[2] * wj3c;
    #pragma unroll
    for (int off = 32; off > 0; off >>= 1){
      ni += __shfl_xor(ni, off);
      nj += __shfl_xor(nj, off);
    }
    if (lane == 0){ fni3_S[s] = ni; fnj3_S[s] = nj; }
  }
}

// ---------------- layer 2 (ego nodes only): aggregate hG rows, then Wnode3 matvec ----------------

__global__ __launch_bounds__(256) void k8_layer2(
    const int* __restrict__ ego, const int* __restrict__ nodeslot, const int* __restrict__ rowptr,
    const int* __restrict__ src_csr, const float* __restrict__ enorm_csr,
    const float* __restrict__ fni1, const float* __restrict__ fnj1,
    const float* __restrict__ fni3_S, const float* __restrict__ fnj3_S,
    const float* __restrict__ hG_S, const float* __restrict__ Wnode3,
    const float* __restrict__ Wfij1, const float* __restrict__ attn1, const float* __restrict__ bias1,
    const float* __restrict__ Wfij3, const float* __restrict__ attn3, const float* __restrict__ bias3,
    float* __restrict__ hG2e)
{
  __shared__ float Wl[192 * 130];        // Wl[c*130+o] = Wnode3[o*192+c]; stride 130 -> 2-way (free)
  __shared__ float aggbuf[4 * 192];
  const int t = threadIdx.x;
  for (int i = t; i < 128 * 192; i += 256){
    int o = i / 192, c = i - o * 192;    // coalesced global read
    Wl[c * 130 + o] = Wnode3[i];
  }
  __syncthreads();

  int lane = t & 63;
  int wv_id = t >> 6;
  int b = blockIdx.x * 4 + wv_id;
  int n = ego[b];
  int slot = nodeslot[n];
  int j0 = rowptr[slot], j1 = rowptr[slot + 1];
  float wf0 = Wfij1[0], wf1 = Wfij1[1], wf2 = Wfij1[2];
  float at0 = attn1[0], at1 = attn1[1], at2 = attn1[2];
  float b0 = bias1[0], b1 = bias1[1], b2 = bias1[2];
  float g0 = Wfij3[0], g1 = Wfij3[1], g2 = Wfij3[2];
  float at3 = attn3[0], bb3 = bias3[0];
  float fj0 = fnj1[n * 3 + 0], fj1 = fnj1[n * 3 + 1], fj2 = fnj1[n * 3 + 2];
  float fnj3v = fnj3_S[slot];

  float lsum = 0.f;
  float acc[3] = {0.f, 0.f, 0.f};
  for (int base = j0; base < j1; base += 64){
    int j = base + lane;
    float w = 0.f; int ss = 0;
    if (j < j1){
      int sn = src_csr[j]; float en = enorm_csr[j];
      float l0 = lrelu(fni1[sn * 3 + 0] + fj0 + en * wf0 + b0);
      float l1 = lrelu(fni1[sn * 3 + 1] + fj1 + en * wf1 + b1);
      float l2 = lrelu(fni1[sn * 3 + 2] + fj2 + en * wf2 + b2);
      float fe3 = l0 * g0 + l1 * g1 + l2 * g2;
      ss = nodeslot[sn];
      float l3 = lrelu(fni3_S[ss] + fnj3v + fe3 + bb3);
      w = expw(l3 * at3);
      lsum += w;
    }
    int c2 = min(64, j1 - base);
    for (int i0 = 0; i0 < c2; i0 += 2){
      float wv[2], fr[2][3];
      #pragma unroll
      for (int u = 0; u < 2; u++){
        int idx = i0 + u;
        int s2 = __shfl(ss, idx);
        wv[u] = __shfl(w, idx);
        bool ok = idx < c2;
        #pragma unroll
        for (int r = 0; r < 3; r++)
          fr[u][r] = ok ? hG_S[(long long)s2 * 192 + r * 64 + lane] : 0.f;
        if (!ok) wv[u] = 0.f;
      }
      #pragma unroll
      for (int u = 0; u < 2; u++)
        #pragma unroll
        for (int r = 0; r < 3; r++) acc[r] += wv[u] * fr[u][r];
    }
  }
  #pragma unroll
  for (int off = 32; off > 0; off >>= 1) lsum += __shfl_xor(lsum, off);
  float inv = (j1 > j0) ? 1.f / lsum : 0.f;

  // write normalized 192-vector to LDS (wave-local), then matvec through Wnode3
  float* aggb = &aggbuf[wv_id * 192];
  #pragma unroll
  for (int r = 0; r < 3; r++) aggb[r * 64 + lane] = acc[r] * inv;
  float o0 = 0.f, o1 = 0.f;
  #pragma unroll 8
  for (int c = 0; c < 192; c++){
    float a = aggb[c];
    o0 += a * Wl[c * 130 + lane];
    o1 += a * Wl[c * 130 + 64 + lane];
  }
  hG2e[b * 128 + lane] = fmaxf(0.f, o0);
  hG2e[b * 128 + 64 + lane] = fmaxf(0.f, o1);
}

// ---------------- fused MLPs + fusion + heads (LDS-staged weights) ----------------

__device__ __forceinline__ void grp_sums2(float v0, float v1, float* red, int t, float& s0, float& s1){
  float a0 = v0, a1 = v1;
  #pragma unroll
  for (int off = 32; off > 0; off >>= 1){
    a0 += __shfl_xor(a0, off);
    a1 += __shfl_xor(a1, off);
  }
  int w = t >> 6;
  if ((t & 63) == 0){ red[w * 2] = a0; red[w * 2 + 1] = a1; }
  __syncthreads();
  int rg = t >> 7;
  s0 = red[rg * 4 + 0] + red[rg * 4 + 2];
  s1 = red[rg * 4 + 1] + red[rg * 4 + 3];
  __syncthreads();
}

__device__ __forceinline__ void ln_relu2(float& z0, float& z1, float g, float bb, float* red, int t){
  float s0, s1;
  grp_sums2(z0, z1, red, t, s0, s1);
  float d0 = z0 - s0 * (1.f / 128.f), d1 = z1 - s1 * (1.f / 128.f);
  float q0, q1;
  grp_sums2(d0 * d0, d1 * d1, red, t, q0, q1);
  z0 = fmaxf(0.f, d0 * rsqrtf(q0 * (1.f / 128.f) + 1e-5f) * g + bb);
  z1 = fmaxf(0.f, d1 * rsqrtf(q1 * (1.f / 128.f) + 1e-5f) * g + bb);
}

template<int K>
__device__ __forceinline__ void stageW(const float* __restrict__ Wg, float* Wl, int t){
  for (int i = t; i < 128 * K; i += 256){
    int oo = i / K, cc = i - oo * K;
    Wl[cc * 129 + oo] = Wg[i];                        // coalesced read, bank-stride-1 write
  }
}

__global__ __launch_bounds__(256) void k_mlp(
    const float* __restrict__ sensor, const float* __restrict__ target, const float* __restrict__ area,
    const float* __restrict__ hG2e,
    const float* __restrict__ Ws1, const float* __restrict__ bs1,
    const float* __restrict__ Ws3, const float* __restrict__ bs3,
    const float* __restrict__ Wt1, const float* __restrict__ bt1,
    const float* __restrict__ Wt2, const float* __restrict__ bt2,
    const float* __restrict__ gM, const float* __restrict__ bM,
    const float* __restrict__ gF, const float* __restrict__ bF,
    const float* __restrict__ Wfc, const float* __restrict__ bfc,
    const float* __restrict__ Wst, const float* __restrict__ bst,
    const float* __restrict__ Wca, const float* __restrict__ bca,
    float* __restrict__ out)
{
  __shared__ float Wl[192 * 129];      // 99 KB
  __shared__ float bufA[4 * 128];
  __shared__ float bufB[4 * 128];
  __shared__ float xc[4 * 384];        // fusion input [hG2e | hS | hT]
  __shared__ float red[8];
  const int t = threadIdx.x;
  const int b0 = blockIdx.x * 4;
  const int o = t & 127, rg = t >> 7;
  const int r0 = rg * 2, r1 = rg * 2 + 1;
  float g_m = gM[o], b_m = bM[o];

  for (int i = t; i < 256; i += 256){
    int r = i >> 6, c = i & 63;
    bufA[r * 128 + c] = sensor[(b0 + r) * 64 + c];
  }
  for (int i = t; i < 512; i += 256){
    int r = i >> 7, c = i & 127;
    xc[r * 384 + c] = hG2e[(b0 + r) * 128 + c];
  }
  stageW<64>(Ws1, Wl, t);
  __syncthreads();

  float z0 = bs1[o], z1 = z0;
  #pragma unroll 8
  for (int c = 0; c < 64; c++){
    float w = Wl[c * 129 + o];
    z0 += w * bufA[r0 * 128 + c];
    z1 += w * bufA[r1 * 128 + c];
  }
  ln_relu2(z0, z1, g_m, b_m, red, t);
  bufB[r0 * 128 + o] = z0; bufB[r1 * 128 + o] = z1;
  __syncthreads();
  stageW<128>(Ws3, Wl, t);
  __syncthreads();

  z0 = bs3[o]; z1 = z0;
  #pragma unroll 8
  for (int c = 0; c < 128; c++){
    float w = Wl[c * 129 + o];
    z0 += w * bufB[r0 * 128 + c];
    z1 += w * bufB[r1 * 128 + c];
  }
  ln_relu2(z0, z1, g_m, b_m, red, t);
  xc[r0 * 384 + 128 + o] = z0; xc[r1 * 384 + 128 + o] = z1;

  for (int i = t; i < 256; i += 256){
    int r = i >> 6, c = i & 63;
    bufA[r * 128 + c] = (c < 32) ? target[(b0 + r) * 32 + c] : area[(b0 + r) * 32 + c - 32];
  }
  __syncthreads();
  stageW<64>(Wt1, Wl, t);
  __syncthreads();

  z0 = bt1[o]; z1 = z0;
  #pragma unroll 8
  for (int c = 0; c < 64; c++){
    float w = Wl[c * 129 + o];
    z0 += w * bufA[r0 * 128 + c];
    z1 += w * bufA[r1 * 128 + c];
  }
  ln_relu2(z0, z1, g_m, b_m, red, t);
  bufB[r0 * 128 + o] = z0; bufB[r1 * 128 + o] = z1;
  __syncthreads();
  stageW<128>(Wt2, Wl, t);
  __syncthreads();

  z0 = bt2[o]; z1 = z0;
  #pragma unroll 8
  for (int c = 0; c < 128; c++){
    float w = Wl[c * 129 + o];
    z0 += w * bufB[r0 * 128 + c];
    z1 += w * bufB[r1 * 128 + c];
  }
  ln_relu2(z0, z1, g_m, b_m, red, t);
  xc[r0 * 384 + 256 + o] = z0; xc[r1 * 384 + 256 + o] = z1;
  __syncthreads();

  float f0 = bfc[o], f1 = f0;
  for (int ch = 0; ch < 2; ch++){
    for (int i = t; i < 128 * 192; i += 256){
      int oo = i / 192, cc = i - oo * 192;
      Wl[cc * 129 + oo] = Wfc[oo * 384 + ch * 192 + cc];
    }
    __syncthreads();
    #pragma unroll 8
    for (int c = 0; c < 192; c++){
      float w = Wl[c * 129 + o];
      f0 += w * xc[r0 * 384 + ch * 192 + c];
      f1 += w * xc[r1 * 384 + ch * 192 + c];
    }
    __syncthreads();
  }
  ln_relu2(f0, f1, gF[o], bF[o], red, t);
  bufB[r0 * 128 + o] = f0; bufB[r1 * 128 + o] = f1;
  __syncthreads();

  for (int i = t; i < 14 * 128; i += 256){
    int oo = i >> 7, cc = i & 127;
    Wl[cc * 15 + oo] = (oo < 6) ? Wst[oo * 128 + cc] : Wca[(oo - 6) * 128 + cc];
  }
  __syncthreads();
  if (o < 14){
    float a0 = (o < 6) ? bst[o] : bca[o - 6];
    float a1 = a0;
    #pragma unroll 8
    for (int c = 0; c < 128; c++){
      float w = Wl[c * 15 + o];
      a0 += w * bufB[r0 * 128 + c];
      a1 += w * bufB[r1 * 128 + c];
    }
    if (o < 6){
      out[(b0 + r0) * 6 + o] = a0;
      out[(b0 + r1) * 6 + o] = a1;
    } else {
      out[N_BATCH * 6 + (b0 + r0) * 8 + o - 6] = a0;
      out[N_BATCH * 6 + (b0 + r1) * 8 + o - 6] = a1;
    }
  }
}

// ---------------- host ----------------

extern "C" void kernel_launch(void* const* d_in, const int* in_sizes, int n_in,
                              void* d_out, int out_size, void* d_ws, size_t ws_size,
                              hipStream_t stream)
{
  const float* feat   = (const float*)d_in[0];
  const float* enorm  = (const float*)d_in[1];
  const float* sensor = (const float*)d_in[2];
  const float* target = (const float*)d_in[3];
  const float* area   = (const float*)d_in[4];
  const int*   src    = (const int*)d_in[5];
  const int*   dst    = (const int*)d_in[6];
  const int*   ego    = (const int*)d_in[7];
  const float* Wni1   = (const float*)d_in[8];
  const float* Wnj1   = (const float*)d_in[9];
  const float* Wfij1  = (const float*)d_in[10];
  const float* Wnode1 = (const float*)d_in[11];
  const float* attn1  = (const float*)d_in[12];
  const float* bias1  = (const float*)d_in[13];
  const float* Wni3   = (const float*)d_in[14];
  const float* Wnj3   = (const float*)d_in[15];
  const float* Wfij3  = (const float*)d_in[16];
  const float* Wnode3 = (const float*)d_in[17];
  const float* attn3  = (const float*)d_in[18];
  const float* bias3  = (const float*)d_in[19];
  const float* Ws1    = (const float*)d_in[20];
  const float* bs1    = (const float*)d_in[21];
  const float* Ws3    = (const float*)d_in[22];
  const float* bs3    = (const float*)d_in[23];
  const float* Wt1    = (const float*)d_in[24];
  const float* bt1    = (const float*)d_in[25];
  const float* Wt2    = (const float*)d_in[26];
  const float* bt2    = (const float*)d_in[27];
  const float* gM     = (const float*)d_in[28];
  const float* bM     = (const float*)d_in[29];
  const float* gF     = (const float*)d_in[30];
  const float* bF     = (const float*)d_in[31];
  const float* Wfc    = (const float*)d_in[32];
  const float* bfc    = (const float*)d_in[33];
  const float* Wst    = (const float*)d_in[34];
  const float* bst    = (const float*)d_in[35];
  const float* Wca    = (const float*)d_in[36];
  const float* bca    = (const float*)d_in[37];
  float* out = (float*)d_out;

  char* ws = (char*)d_ws;
  size_t off = 0;
  auto alloc = [&](size_t bytes) -> size_t {
    size_t o = off;
    off = (off + bytes + 255) & ~(size_t)255;
    return o;
  };

  // zero-init region (must be first, contiguous from 0)
  size_t o_meta    = alloc(256);
  size_t o_egoflag = alloc((size_t)N_NODES * 4);
  size_t o_Sflag   = alloc((size_t)N_NODES * 4);
  size_t o_cnt     = alloc((size_t)(N_NODES + 1) * 4);
  size_t o_cursor  = alloc((size_t)N_NODES * 4);
  size_t zero_bytes = off;
  // non-zeroed fixed arrays
  size_t o_fni1    = alloc((size_t)N_NODES * 3 * 4);
  size_t o_fnj1    = alloc((size_t)N_NODES * 3 * 4);
  size_t o_nodeslot= alloc((size_t)N_NODES * 4);
  size_t o_S_ids   = alloc((size_t)N_NODES * 4);
  size_t o_rowptr  = alloc((size_t)(N_NODES + 1) * 4);
  size_t o_fni3    = alloc((size_t)N_NODES * 4);
  size_t o_fnj3    = alloc((size_t)N_NODES * 4);
  size_t o_hG2e    = alloc((size_t)N_BATCH * 128 * 4);
  // dynamic capacity arrays
  size_t rem = (ws_size > off) ? ws_size - off : 0;
  size_t ecap = rem / 40;                       // ~20% to edge arrays (8 B/edge)
  if (ecap > (size_t)N_EDGES) ecap = N_EDGES;
  if (ecap < 1) ecap = 1;
  size_t o_src_csr   = alloc(ecap * 4);
  size_t o_enorm_csr = alloc(ecap * 4);
  size_t rem2 = (ws_size > off) ? ws_size - off : 0;
  size_t scap = rem2 / 768;                     // 768 B per slot (hG_S only)
  if (scap > (size_t)N_NODES) scap = N_NODES;
  if (scap < 1) scap = 1;
  size_t o_hG_S  = alloc(scap * 768);

  int*   meta      = (int*)(ws + o_meta);
  int*   egoflag   = (int*)(ws + o_egoflag);
  int*   Sflag     = (int*)(ws + o_Sflag);
  int*   cnt       = (int*)(ws + o_cnt);
  int*   cursor    = (int*)(ws + o_cursor);
  float* fni1      = (float*)(ws + o_fni1);
  float* fnj1      = (float*)(ws + o_fnj1);
  int*   nodeslot  = (int*)(ws + o_nodeslot);
  int*   S_ids     = (int*)(ws + o_S_ids);
  int*   rowptr    = (int*)(ws + o_rowptr);
  float* fni3_S    = (float*)(ws + o_fni3);
  float* fnj3_S    = (float*)(ws + o_fnj3);
  float* hG2e      = (float*)(ws + o_hG2e);
  int*   src_csr   = (int*)(ws + o_src_csr);
  float* enorm_csr = (float*)(ws + o_enorm_csr);
  float* hG_S      = (float*)(ws + o_hG_S);

  hipMemsetAsync(ws, 0, zero_bytes, stream);

  k_pre<<<(N_NODES + 255) / 256, 256, 0, stream>>>(ego, egoflag, Sflag, feat, Wni1, Wnj1, fni1, fnj1);
  k_mark_S<<<(N_EDGES / 4 + 255) / 256, 256, 0, stream>>>(src, dst, egoflag, Sflag);
  k_compact<<<(N_NODES + 255) / 256, 256, 0, stream>>>(Sflag, nodeslot, S_ids, meta);
  k_count<<<(N_EDGES / 4 + 255) / 256, 256, 0, stream>>>(src, dst, Sflag, nodeslot, cnt);
  k_scan<<<1, 1024, 0, stream>>>(cnt, rowptr, meta);
  k_fill<<<(N_EDGES / 4 + 255) / 256, 256, 0, stream>>>(src, dst, enorm, Sflag, nodeslot,
                                                        rowptr, cursor, src_csr, enorm_csr);
  k6_layer1<<<2048, 256, 0, stream>>>(feat, fni1, fnj1, S_ids, rowptr, src_csr, enorm_csr,
                                      Wnode1, Wfij1, attn1, bias1, Wni3, Wnj3, meta,
                                      hG_S, fni3_S, fnj3_S);
  k8_layer2<<<N_BATCH / 4, 256, 0, stream>>>(
      ego, nodeslot, rowptr, src_csr, enorm_csr, fni1, fnj1,
      fni3_S, fnj3_S, hG_S, Wnode3, Wfij1, attn1, bias1, Wfij3, attn3, bias3, hG2e);
  k_mlp<<<N_BATCH / 4, 256, 0, stream>>>(sensor, target, area, hG2e,
                                         Ws1, bs1, Ws3, bs3, Wt1, bt1, Wt2, bt2,
                                         gM, bM, gF, bF, Wfc, bfc, Wst, bst, Wca, bca, out);
  (void)in_sizes; (void)n_in; (void)out_size;
}